// Round 6
// baseline (145.482 us; speedup 1.0000x reference)
//
#include <hip/hip_runtime.h>
#include <math.h>

#define D_MODEL 4096
#define NEXP    64
#define NTOK    16384
#define BT      16                 // tokens per block
#define BK      128                // K per step
#define NSTEP   (D_MODEL / BK)     // 32
#define LGSTR   68                 // logits LDS stride (pad)

typedef __attribute__((ext_vector_type(8))) short  bf16x8;
typedef __attribute__((ext_vector_type(4))) float  f32x4;

__device__ __forceinline__ unsigned short f2bf_rn(float f) {
    union { float f; unsigned u; } v; v.f = f;
    unsigned r = v.u + 0x7fffu + ((v.u >> 16) & 1u);
    return (unsigned short)(r >> 16);
}
__device__ __forceinline__ float bf2f(unsigned short h) {
    union { unsigned u; float f; } v; v.u = ((unsigned)h) << 16;
    return v.f;
}
// split two floats into packed bf16 hi-word and lo-word (RNE both)
__device__ __forceinline__ void split2(float f0, float f1, unsigned& hw, unsigned& lw) {
    unsigned short h0 = f2bf_rn(f0), h1 = f2bf_rn(f1);
    unsigned short l0 = f2bf_rn(f0 - bf2f(h0)), l1 = f2bf_rn(f1 - bf2f(h1));
    hw = (unsigned)h0 | ((unsigned)h1 << 16);
    lw = (unsigned)l0 | ((unsigned)l1 << 16);
}

// (v,i) pair merge keeping jax.lax.top_k semantics (lower index wins ties)
__device__ __forceinline__ void top2_merge(float& v1, int& i1, float& v2, int& i2,
                                           float ov1, int oi1, float ov2, int oi2) {
    if (ov1 > v1 || (ov1 == v1 && oi1 < i1)) {
        float nv2 = v1; int ni2 = i1;
        if (ov2 > nv2 || (ov2 == nv2 && oi2 < ni2)) { nv2 = ov2; ni2 = oi2; }
        v1 = ov1; i1 = oi1; v2 = nv2; i2 = ni2;
    } else {
        if (ov1 > v2 || (ov1 == v2 && oi1 < i2)) { v2 = ov1; i2 = oi1; }
    }
}

// ---------------------------------------------------------------------------
// k0: split W into bf16 hi/lo halves in ws; block 0 also zeros expert_counts.
// ---------------------------------------------------------------------------
__global__ __launch_bounds__(256)
void k0_split_w(const float* __restrict__ W, unsigned short* __restrict__ ws,
                float* __restrict__ out) {
    if (blockIdx.x == 0 && threadIdx.x < NEXP)
        out[(size_t)2 * NTOK * NEXP + threadIdx.x] = 0.f;
    int i = (blockIdx.x * 256 + threadIdx.x) * 4;
    float4 v = *reinterpret_cast<const float4*>(&W[i]);
    unsigned short h[4], l[4];
    float f[4] = {v.x, v.y, v.z, v.w};
#pragma unroll
    for (int k = 0; k < 4; ++k) {
        h[k] = f2bf_rn(f[k]);
        l[k] = f2bf_rn(f[k] - bf2f(h[k]));
    }
    *reinterpret_cast<short4*>(&ws[i])                  = make_short4(h[0], h[1], h[2], h[3]);
    *reinterpret_cast<short4*>(&ws[NEXP * D_MODEL + i]) = make_short4(l[0], l[1], l[2], l[3]);
}

// ---------------------------------------------------------------------------
// k1: fused router. 256-thread blocks (4 waves), BT=16 tokens, BK=128.
// Grid 1024 -> 4 independent blocks/CU: each SIMD hosts 4 waves from 4
// different barrier groups, so a block's barrier stall overlaps with other
// blocks' compute (TLP does the latency hiding, not fragile in-wave ILP).
// Wave w = expert strip 16w..16w+15, all 16 tokens. x staged to LDS as
// pre-split bf16 hi/lo (once per tile); inner loop ds_read_b128 -> MFMA.
// One barrier per step (write-late double buffer).
// ---------------------------------------------------------------------------
__global__ __launch_bounds__(256, 4)
void k1_fused(const float* __restrict__ x, const unsigned short* __restrict__ wsplit,
              const float* __restrict__ bias, float* __restrict__ out) {
    __shared__ unsigned xh[2][BT * 64];   // 2 x 4 KiB (64 uints = 128 bf16/row)
    __shared__ unsigned xl[2][BT * 64];   // 2 x 4 KiB
    __shared__ float lg[BT * LGSTR];      // 4352 B
    __shared__ float cnt[NEXP];

    const int tid  = threadIdx.x;
    const int t0   = blockIdx.x * BT;
    const int w    = tid >> 6;            // expert strip 0..3
    const int lane = tid & 63;
    const int rowl = lane & 15;
    const int grp  = lane >> 4;           // 0..3 (K-slot)

    if (tid < NEXP) cnt[tid] = 0.f;

    // staging geometry: thread -> (row=tid>>4, 8-float chunk p=tid&15),
    // XOR-swizzled chunk position (both sides exactly 8 bank-cycles).
    const int s_row = tid >> 4;
    const int s_p   = tid & 15;
    const int s_idx = s_row * 64 + ((s_p ^ (s_row & 7)) << 2);
    const float* gsrc = x + (size_t)(t0 + s_row) * D_MODEL + s_p * 8;

    // A-fragment read offsets (same swizzle), chunk c = f*4+grp
    const int a_sw = rowl & 7;
    int aoff[4];
#pragma unroll
    for (int f = 0; f < 4; ++f)
        aoff[f] = rowl * 64 + (((f * 4 + grp) ^ a_sw) << 2);

    // B pointers (bf16 hi/lo W, L2/L3-resident)
    const int e = w * 16 + rowl;
    const unsigned short* bhp = wsplit + (size_t)e * D_MODEL + grp * 8;
    const unsigned short* blp = bhp + (size_t)NEXP * D_MODEL;

    f32x4 acc = {0.f, 0.f, 0.f, 0.f};

#define SPLIT_WRITE(b, va, vb) do {                                       \
    unsigned h0, l0, h1, l1, h2, l2, h3, l3;                              \
    split2((va).x, (va).y, h0, l0);                                       \
    split2((va).z, (va).w, h1, l1);                                       \
    split2((vb).x, (vb).y, h2, l2);                                       \
    split2((vb).z, (vb).w, h3, l3);                                       \
    *reinterpret_cast<uint4*>(&xh[b][s_idx]) = make_uint4(h0, h1, h2, h3);\
    *reinterpret_cast<uint4*>(&xl[b][s_idx]) = make_uint4(l0, l1, l2, l3);\
} while (0)

    // prologue: stage step 0 into buf 0
    {
        float4 va = *reinterpret_cast<const float4*>(gsrc);
        float4 vb = *reinterpret_cast<const float4*>(gsrc + 4);
        SPLIT_WRITE(0, va, vb);
    }
    __syncthreads();

    for (int t = 0; t < NSTEP; ++t) {
        // issue next x-tile loads EARLY (used after compute: T14 split)
        const int tn = (t + 1 < NSTEP) ? t + 1 : t;
        float4 na = *reinterpret_cast<const float4*>(gsrc + (size_t)tn * BK);
        float4 nb = *reinterpret_cast<const float4*>(gsrc + (size_t)tn * BK + 4);

        // compute on buf (t&1)
        const unsigned* bufh = &xh[t & 1][0];
        const unsigned* bufl = &xl[t & 1][0];
        const int kb = t * BK;
#pragma unroll
        for (int f = 0; f < 4; ++f) {
            bf16x8 ah = *reinterpret_cast<const bf16x8*>(&bufh[aoff[f]]);
            bf16x8 al = *reinterpret_cast<const bf16x8*>(&bufl[aoff[f]]);
            bf16x8 bh = *reinterpret_cast<const bf16x8*>(bhp + kb + f * 32);
            bf16x8 bl = *reinterpret_cast<const bf16x8*>(blp + kb + f * 32);
            acc = __builtin_amdgcn_mfma_f32_16x16x32_bf16(ah, bh, acc, 0, 0, 0);
            acc = __builtin_amdgcn_mfma_f32_16x16x32_bf16(ah, bl, acc, 0, 0, 0);
            acc = __builtin_amdgcn_mfma_f32_16x16x32_bf16(al, bh, acc, 0, 0, 0);
        }

        // write-late: stage step t+1 into the other buffer, then ONE barrier
        if (t + 1 < NSTEP) {
            SPLIT_WRITE((t + 1) & 1, na, nb);
            __syncthreads();
        }
    }

    // ---- epilogue: logits tile -> LDS, fused softmax + top2 (validated) ----
#pragma unroll
    for (int i = 0; i < 4; ++i)
        lg[(grp * 4 + i) * LGSTR + w * 16 + rowl] = acc[i];
    __syncthreads();

    const int token = tid >> 4;           // 0..15
    const int j     = tid & 15;           // 16 threads per token
    float4 v4 = *reinterpret_cast<const float4*>(&lg[token * LGSTR + j * 4]);
    float lv[4] = {v4.x + bias[j * 4 + 0], v4.y + bias[j * 4 + 1],
                   v4.z + bias[j * 4 + 2], v4.w + bias[j * 4 + 3]};

    float v1 = lv[0], v2 = -INFINITY;
    int   i1 = j * 4, i2 = 1 << 30;
#pragma unroll
    for (int k = 1; k < 4; ++k) {
        if (lv[k] > v1)      { v2 = v1; i2 = i1; v1 = lv[k]; i1 = j * 4 + k; }
        else if (lv[k] > v2) { v2 = lv[k]; i2 = j * 4 + k; }
    }
#pragma unroll
    for (int mask = 1; mask < 16; mask <<= 1) {
        float ov1 = __shfl_xor(v1, mask);
        int   oi1 = __shfl_xor(i1, mask);
        float ov2 = __shfl_xor(v2, mask);
        int   oi2 = __shfl_xor(i2, mask);
        top2_merge(v1, i1, v2, i2, ov1, oi1, ov2, oi2);
    }
    float s = 0.f;
#pragma unroll
    for (int k = 0; k < 4; ++k) s += __expf(lv[k] - v1);
#pragma unroll
    for (int mask = 1; mask < 16; mask <<= 1) s += __shfl_xor(s, mask);

    const float invS = 1.f / s;
    const float s1 = invS;
    const float s2 = __expf(v2 - v1) * invS;

    const int tg = t0 + token;
    float4 o = make_float4(0.f, 0.f, 0.f, 0.f);
    if ((i1 >> 2) == j) (&o.x)[i1 & 3] = s1;
    if ((i2 >> 2) == j) (&o.x)[i2 & 3] = s2;
    *reinterpret_cast<float4*>(&out[(size_t)tg * NEXP + j * 4]) = o;
    *reinterpret_cast<float4*>(&out[(size_t)NTOK * NEXP + (size_t)tg * NEXP + j * 4]) = o;

    if (j == 0) {
        atomicAdd(&cnt[i1], s1);
        atomicAdd(&cnt[i2], s2);
    }
    __syncthreads();
    if (tid < NEXP)
        atomicAdd(&out[(size_t)2 * NTOK * NEXP + tid], cnt[tid]);
}

// ---------------------------------------------------------------------------
extern "C" void kernel_launch(void* const* d_in, const int* in_sizes, int n_in,
                              void* d_out, int out_size, void* d_ws, size_t ws_size,
                              hipStream_t stream) {
    const float* x = (const float*)d_in[0];
    const float* W = (const float*)d_in[1];
    const float* b = (const float*)d_in[2];
    float* out = (float*)d_out;
    unsigned short* ws = (unsigned short*)d_ws;   // 1 MiB

    k0_split_w<<<NEXP * D_MODEL / (256 * 4), 256, 0, stream>>>(W, ws, out);
    k1_fused<<<NTOK / BT, 256, 0, stream>>>(x, ws, b, out);
}

// Round 7
// 104.674 us; speedup vs baseline: 1.3899x; 1.3899x over previous
//
#include <hip/hip_runtime.h>
#include <math.h>

#define D_MODEL 4096
#define NEXP    64
#define NTOK    16384
#define KSPLIT  16
#define KS      256                // K per block (slice)
#define BMT     256                // tokens per block

typedef __attribute__((ext_vector_type(8))) short  bf16x8;
typedef __attribute__((ext_vector_type(4))) float  f32x4;

__device__ __forceinline__ unsigned short f2bf_rn(float f) {
    union { float f; unsigned u; } v; v.f = f;
    unsigned r = v.u + 0x7fffu + ((v.u >> 16) & 1u);
    return (unsigned short)(r >> 16);
}
__device__ __forceinline__ float bf2f(unsigned short h) {
    union { unsigned u; float f; } v; v.u = ((unsigned)h) << 16;
    return v.f;
}
// split two floats into packed bf16 hi-word and lo-word (RNE both)
__device__ __forceinline__ void split2(float f0, float f1, unsigned& hw, unsigned& lw) {
    unsigned short h0 = f2bf_rn(f0), h1 = f2bf_rn(f1);
    unsigned short l0 = f2bf_rn(f0 - bf2f(h0)), l1 = f2bf_rn(f1 - bf2f(h1));
    hw = (unsigned)h0 | ((unsigned)h1 << 16);
    lw = (unsigned)l0 | ((unsigned)l1 << 16);
}

// ---------------------------------------------------------------------------
// k0: split W into bf16 hi/lo halves; zero the logits accumulator (in ws) and
// the expert_counts tail of out.   65536 threads.
// ---------------------------------------------------------------------------
__global__ __launch_bounds__(256)
void k0_prep(const float* __restrict__ W, unsigned short* __restrict__ ws,
             float* __restrict__ logits, float* __restrict__ out) {
    const int gid = blockIdx.x * 256 + threadIdx.x;
    if (blockIdx.x == 0 && threadIdx.x < NEXP)
        out[(size_t)2 * NTOK * NEXP + threadIdx.x] = 0.f;
    // zero logits: 1M floats, 16 per thread
    float4 z = make_float4(0.f, 0.f, 0.f, 0.f);
    float* lz = logits + (size_t)gid * 16;
#pragma unroll
    for (int k = 0; k < 4; ++k)
        *reinterpret_cast<float4*>(&lz[k * 4]) = z;
    // W split
    int i = gid * 4;
    float4 v = *reinterpret_cast<const float4*>(&W[i]);
    unsigned short h[4], l[4];
    float f[4] = {v.x, v.y, v.z, v.w};
#pragma unroll
    for (int k = 0; k < 4; ++k) {
        h[k] = f2bf_rn(f[k]);
        l[k] = f2bf_rn(f[k] - bf2f(h[k]));
    }
    *reinterpret_cast<short4*>(&ws[i])                  = make_short4(h[0], h[1], h[2], h[3]);
    *reinterpret_cast<short4*>(&ws[NEXP * D_MODEL + i]) = make_short4(l[0], l[1], l[2], l[3]);
}

// ---------------------------------------------------------------------------
// k1: split-K GEMM partial. Block = 256 tokens x 64 experts x K-slice 256.
// W-slice (hi+lo, 64 KB) LDS-resident, loaded ONCE. 8 waves x 32 tokens,
// full-E per wave; x global->register (each row used by exactly one wave).
// NO barriers in the K-loop -> 16 independent waves/CU hide all latency.
// Partial logits accumulate via fp32 atomicAdd into ws (zeroed by k0).
// ---------------------------------------------------------------------------
__global__ __launch_bounds__(512, 4)
void k1_gemm(const float* __restrict__ x, const unsigned short* __restrict__ wsplit,
             float* __restrict__ logits) {
    __shared__ uint4 whi[NEXP * 32];   // 32 KiB: [e][kchunk] 16B chunks, swizzled
    __shared__ uint4 wlo[NEXP * 32];   // 32 KiB

    const int tid = threadIdx.x;
    const int t0  = (blockIdx.x >> 4) * BMT;
    const int ks0 = (blockIdx.x & 15) * KS;

    // ---- W-slice load (once): 4096 chunks of 16B, 8 per thread ----
#pragma unroll
    for (int i = 0; i < 4; ++i) {
        int p  = tid + i * 512;            // 0..2047
        int e  = p >> 5;                   // expert row
        int c  = p & 31;                   // k-chunk (8 bf16)
        int cs = (c & 24) | ((c & 7) ^ (e & 7));   // XOR swizzle (G4/T2)
        const unsigned short* src = wsplit + (size_t)e * D_MODEL + ks0 + c * 8;
        whi[e * 32 + cs] = *reinterpret_cast<const uint4*>(src);
        wlo[e * 32 + cs] = *reinterpret_cast<const uint4*>(src + NEXP * D_MODEL);
    }
    __syncthreads();                       // the ONLY barrier

    const int lane = tid & 63;
    const int rowl = lane & 15;
    const int grp  = lane >> 4;            // k-slot
    const int wtok = t0 + (tid >> 6) * 32;

    const float* xp0 = x + (size_t)(wtok + rowl) * D_MODEL + ks0 + grp * 8;
    const float* xp1 = xp0 + (size_t)16 * D_MODEL;

    f32x4 acc[2][4];
#pragma unroll
    for (int m = 0; m < 2; ++m)
#pragma unroll
        for (int n = 0; n < 4; ++n)
            acc[m][n] = (f32x4){0.f, 0.f, 0.f, 0.f};

#pragma unroll
    for (int kb = 0; kb < 8; ++kb) {       // 8 x K=32
        union { bf16x8 v; unsigned u[4]; } ah0, al0, ah1, al1;
        {
            f32x4 c0 = *reinterpret_cast<const f32x4*>(xp0 + kb * 32);
            f32x4 c1 = *reinterpret_cast<const f32x4*>(xp0 + kb * 32 + 4);
            split2(c0.x, c0.y, ah0.u[0], al0.u[0]);
            split2(c0.z, c0.w, ah0.u[1], al0.u[1]);
            split2(c1.x, c1.y, ah0.u[2], al0.u[2]);
            split2(c1.z, c1.w, ah0.u[3], al0.u[3]);
        }
        {
            f32x4 c0 = *reinterpret_cast<const f32x4*>(xp1 + kb * 32);
            f32x4 c1 = *reinterpret_cast<const f32x4*>(xp1 + kb * 32 + 4);
            split2(c0.x, c0.y, ah1.u[0], al1.u[0]);
            split2(c0.z, c0.w, ah1.u[1], al1.u[1]);
            split2(c1.x, c1.y, ah1.u[2], al1.u[2]);
            split2(c1.z, c1.w, ah1.u[3], al1.u[3]);
        }
        const int c  = kb * 4 + grp;
        const int cs = (c & 24) | ((c & 7) ^ (rowl & 7));   // e&7 == rowl&7
#pragma unroll
        for (int n = 0; n < 4; ++n) {
            const int idx = (n * 16 + rowl) * 32 + cs;
            bf16x8 bh = *reinterpret_cast<const bf16x8*>(&whi[idx]);
            bf16x8 bl = *reinterpret_cast<const bf16x8*>(&wlo[idx]);
            acc[0][n] = __builtin_amdgcn_mfma_f32_16x16x32_bf16(ah0.v, bh, acc[0][n], 0, 0, 0);
            acc[0][n] = __builtin_amdgcn_mfma_f32_16x16x32_bf16(ah0.v, bl, acc[0][n], 0, 0, 0);
            acc[0][n] = __builtin_amdgcn_mfma_f32_16x16x32_bf16(al0.v, bh, acc[0][n], 0, 0, 0);
            acc[1][n] = __builtin_amdgcn_mfma_f32_16x16x32_bf16(ah1.v, bh, acc[1][n], 0, 0, 0);
            acc[1][n] = __builtin_amdgcn_mfma_f32_16x16x32_bf16(ah1.v, bl, acc[1][n], 0, 0, 0);
            acc[1][n] = __builtin_amdgcn_mfma_f32_16x16x32_bf16(al1.v, bh, acc[1][n], 0, 0, 0);
        }
    }

    // partial-logit accumulate (D: row = token = grp*4+i, col = expert = rowl
    // -- convention validated r2/r4/r6)
#pragma unroll
    for (int m = 0; m < 2; ++m)
#pragma unroll
        for (int n = 0; n < 4; ++n)
#pragma unroll
            for (int i = 0; i < 4; ++i) {
                const int t = wtok + m * 16 + grp * 4 + i;
                const int e = n * 16 + rowl;
                atomicAdd(&logits[(size_t)t * NEXP + e], acc[m][n][i]);
            }
}

// ---------------------------------------------------------------------------
// k2: per-token bias + softmax + top-2 + dense scatter + counts (validated r1)
// ---------------------------------------------------------------------------
__global__ __launch_bounds__(256)
void k2_softmax_top2(const float* __restrict__ logits, const float* __restrict__ bias,
                     float* __restrict__ out) {
    const int t = blockIdx.x * 256 + threadIdx.x;
    __shared__ float cnt[NEXP];
    __shared__ float bs[NEXP];
    if (threadIdx.x < NEXP) {
        cnt[threadIdx.x] = 0.f;
        bs[threadIdx.x]  = bias[threadIdx.x];
    }
    __syncthreads();

    float l[NEXP];
    const float* lp = logits + (size_t)t * NEXP;
#pragma unroll
    for (int g = 0; g < 16; ++g) {
        float4 v = *reinterpret_cast<const float4*>(&lp[g * 4]);
        l[4 * g + 0] = v.x + bs[4 * g + 0];
        l[4 * g + 1] = v.y + bs[4 * g + 1];
        l[4 * g + 2] = v.z + bs[4 * g + 2];
        l[4 * g + 3] = v.w + bs[4 * g + 3];
    }

    float m = l[0];
#pragma unroll
    for (int e = 1; e < NEXP; ++e) m = fmaxf(m, l[e]);

    float sum = 0.f;
#pragma unroll
    for (int e = 0; e < NEXP; ++e) sum += __expf(l[e] - m);

    float v1 = -INFINITY, v2 = -INFINITY;
    int   i1 = 0, i2 = 0;
#pragma unroll
    for (int e = 0; e < NEXP; ++e) {
        if (l[e] > v1) { v2 = v1; i2 = i1; v1 = l[e]; i1 = e; }
        else if (l[e] > v2) { v2 = l[e]; i2 = e; }
    }
    const float inv = 1.f / sum;
    const float s1 = __expf(v1 - m) * inv;
    const float s2 = __expf(v2 - m) * inv;

    float* disp = out + (size_t)t * NEXP;
    float* comb = out + (size_t)NTOK * NEXP + (size_t)t * NEXP;
#pragma unroll
    for (int g = 0; g < 16; ++g) {
        float4 o = make_float4(0.f, 0.f, 0.f, 0.f);
        if ((i1 >> 2) == g) (&o.x)[i1 & 3] = s1;
        if ((i2 >> 2) == g) (&o.x)[i2 & 3] = s2;
        *reinterpret_cast<float4*>(&disp[g * 4]) = o;
        *reinterpret_cast<float4*>(&comb[g * 4]) = o;
    }

    atomicAdd(&cnt[i1], s1);
    atomicAdd(&cnt[i2], s2);
    __syncthreads();
    if (threadIdx.x < NEXP)
        atomicAdd(&out[(size_t)2 * NTOK * NEXP + threadIdx.x], cnt[threadIdx.x]);
}

// ---------------------------------------------------------------------------
extern "C" void kernel_launch(void* const* d_in, const int* in_sizes, int n_in,
                              void* d_out, int out_size, void* d_ws, size_t ws_size,
                              hipStream_t stream) {
    const float* x = (const float*)d_in[0];
    const float* W = (const float*)d_in[1];
    const float* b = (const float*)d_in[2];
    float* out = (float*)d_out;
    unsigned short* ws = (unsigned short*)d_ws;          // 1 MiB W-split
    float* logits = (float*)(ws + 2 * NEXP * D_MODEL);   // + 4 MiB partials

    k0_prep<<<256, 256, 0, stream>>>(W, ws, logits, out);
    k1_gemm<<<(NTOK / BMT) * KSPLIT, 512, 0, stream>>>(x, ws, logits);
    k2_softmax_top2<<<NTOK / 256, 256, 0, stream>>>(logits, b, out);
}